// Round 3
// baseline (280.808 us; speedup 1.0000x reference)
//
#include <hip/hip_runtime.h>
#include <hip/hip_bf16.h>

// GLOM level-1: fused similarity-attention (prob-reweighted) + InstanceNorm.
// B=16, C=128, H=32, W=40 -> N=1280.
//
// attn kernel: grid 256 (16 batches x 16 row-tiles of 80), block 256 (16x16).
//   e[n,m] = exp(dot(x_n,x_m)/(1.2*sqrt(128)))      (no max-sub; |logit| <~ 13)
//   S[n] = sum_m e, T[n] = sum_m e*p
//   agg[n,c] = sum_m e*p*X[c][m] / (T + 1e-8*S)
//   == softmax -> *probs -> renormalize(+1e-8) exactly (denominator cancels).
// micro-tile: 5 rows x 8 cols (QK^T), 5 rows x 8 chans (PV)
//   -> 13 DS insts / 160 FMAs per chunk (LDS-issue balanced vs 4-wave VALU).
// inorm kernel: exact two-pass InstanceNorm in-place on out.

#define B_ 16
#define C_ 128
#define N_ 1280
#define BN 80          // rows per block (16 tiles/batch * 16 batches = 256 blocks)
#define BM 128         // m-tile
#define NT 10          // N_/BM
#define AMLD 132       // +4 pad: stride 132 mod 32 = 4 -> 2-way (free) on all reads

__global__ __launch_bounds__(256, 1) void glom_attn_kernel(
    const float* __restrict__ x, const float* __restrict__ probs,
    float* __restrict__ out)
{
    // An4[c4][i] = {X[4c4][n0+i], X[4c4+1][n0+i], X[4c4+2][n0+i], X[4c4+3][n0+i]}
    __shared__ float4 An4[32][BN];                    // 40960 B (b128 broadcast a-reads)
    __shared__ __attribute__((aligned(16))) float Am[C_][AMLD];  // 67584 B  Am[c][j]=X[c][m0+j]
    __shared__ __attribute__((aligned(16))) float Wt[BN][AMLD];  // 42240 B  w-tile

    const int tid = threadIdx.x;
    const int ti  = tid >> 4;          // 0..15 : row group (rows ti+16k, k<5)
    const int tj  = tid & 15;          // 0..15 : col group / chan group
    const int tj4 = tj * 4;

    // XCD-locality: blocks with equal (L&7) share an XCD -> same 2 batches' x in L2
    const int L  = blockIdx.x;
    const int b  = (L & 7) + 8 * (L >> 7);
    const int nt = (L >> 3) & 15;
    const int n0 = nt * BN;

    const float* Xb = x + (size_t)b * C_ * N_;

    // ---- stage An4 (once): 128 ch x 80 rows, channel-quad interleaved ----
    #pragma unroll
    for (int k = 0; k < 10; ++k) {
        int f  = tid + 256 * k;        // float4 index 0..2559
        int c  = f / 20;
        int i4 = f % 20;
        const float4 v = *reinterpret_cast<const float4*>(Xb + c * N_ + n0 + i4 * 4);
        float* dst = reinterpret_cast<float*>(&An4[c >> 2][i4 * 4]) + (c & 3);
        dst[0] = v.x; dst[4] = v.y; dst[8] = v.z; dst[12] = v.w;
    }

    float acc[5][8];
    #pragma unroll
    for (int k = 0; k < 5; ++k)
        #pragma unroll
        for (int cc = 0; cc < 8; ++cc) acc[k][cc] = 0.0f;
    float Ssum[5] = {0.f, 0.f, 0.f, 0.f, 0.f};
    float Tsum[5] = {0.f, 0.f, 0.f, 0.f, 0.f};

    const float inv_scale = 0.07365695637359846f;   // 1/(1.2*sqrt(128))

    for (int mt = 0; mt < NT; ++mt) {
        const int m0 = mt * BM;
        __syncthreads();                             // prev PV reads done before restage
        // ---- stage Am tile: 128 ch x 128 cols ----
        #pragma unroll
        for (int k = 0; k < 16; ++k) {
            int f  = tid + 256 * k;                  // 0..4095
            int c  = f >> 5;
            int j4 = f & 31;
            const float4 v = *reinterpret_cast<const float4*>(Xb + c * N_ + m0 + j4 * 4);
            *reinterpret_cast<float4*>(&Am[c][j4 * 4]) = v;
        }
        __syncthreads();

        // ---- QK^T: s[k][j] = sum_c An[c][ti+16k] * Am[c][cols] ----
        // cols: tj4+0..3 (low) and tj4+64..67 (high)
        float s[5][8];
        #pragma unroll
        for (int k = 0; k < 5; ++k)
            #pragma unroll
            for (int j = 0; j < 8; ++j) s[k][j] = 0.0f;

        #pragma unroll 4
        for (int c4 = 0; c4 < 32; ++c4) {
            float4 a[5];
            #pragma unroll
            for (int k = 0; k < 5; ++k) a[k] = An4[c4][ti + 16 * k];
            #pragma unroll
            for (int p = 0; p < 4; ++p) {
                const float4 bl = *reinterpret_cast<const float4*>(&Am[4 * c4 + p][tj4]);
                const float4 bh = *reinterpret_cast<const float4*>(&Am[4 * c4 + p][tj4 + 64]);
                #pragma unroll
                for (int k = 0; k < 5; ++k) {
                    const float ak = reinterpret_cast<const float*>(&a[k])[p];
                    s[k][0] += ak * bl.x; s[k][1] += ak * bl.y;
                    s[k][2] += ak * bl.z; s[k][3] += ak * bl.w;
                    s[k][4] += ak * bh.x; s[k][5] += ak * bh.y;
                    s[k][6] += ak * bh.z; s[k][7] += ak * bh.w;
                }
            }
        }

        // ---- exp, *probs, partial S/T, write w tile (same-wave rows only) ----
        #pragma unroll
        for (int k = 0; k < 5; ++k) {
            const int gi = n0 + ti + 16 * k;
            const float* pr = probs + (size_t)gi * N_ + m0;
            const float4 pl = *reinterpret_cast<const float4*>(pr + tj4);
            const float4 ph = *reinterpret_cast<const float4*>(pr + tj4 + 64);
            float e[8];
            #pragma unroll
            for (int j = 0; j < 8; ++j) e[j] = __expf(s[k][j] * inv_scale);
            Ssum[k] += ((e[0] + e[1]) + (e[2] + e[3])) + ((e[4] + e[5]) + (e[6] + e[7]));
            float4 wl, wh;
            wl.x = e[0] * pl.x; wl.y = e[1] * pl.y; wl.z = e[2] * pl.z; wl.w = e[3] * pl.w;
            wh.x = e[4] * ph.x; wh.y = e[5] * ph.y; wh.z = e[6] * ph.z; wh.w = e[7] * ph.w;
            Tsum[k] += ((wl.x + wl.y) + (wl.z + wl.w)) + ((wh.x + wh.y) + (wh.z + wh.w));
            *reinterpret_cast<float4*>(&Wt[ti + 16 * k][tj4]) = wl;
            *reinterpret_cast<float4*>(&Wt[ti + 16 * k][tj4 + 64]) = wh;
        }
        // rows {ti+16k} written & read entirely within this wave -> no barrier

        // ---- PV: acc[k][cc] += sum_m Wt[row][m] * Am[tj+16cc][m] ----
        #pragma unroll 2
        for (int m4 = 0; m4 < 32; ++m4) {
            float4 wv[5];
            #pragma unroll
            for (int k = 0; k < 5; ++k)
                wv[k] = *reinterpret_cast<const float4*>(&Wt[ti + 16 * k][m4 * 4]);
            float4 av[8];
            #pragma unroll
            for (int cc = 0; cc < 8; ++cc)
                av[cc] = *reinterpret_cast<const float4*>(&Am[tj + 16 * cc][m4 * 4]);
            #pragma unroll
            for (int k = 0; k < 5; ++k)
                #pragma unroll
                for (int cc = 0; cc < 8; ++cc) {
                    acc[k][cc] += wv[k].x * av[cc].x;
                    acc[k][cc] += wv[k].y * av[cc].y;
                    acc[k][cc] += wv[k].z * av[cc].z;
                    acc[k][cc] += wv[k].w * av[cc].w;
                }
        }
    }

    // ---- reduce S,T over the 16-lane row group ----
    #pragma unroll
    for (int k = 0; k < 5; ++k) {
        #pragma unroll
        for (int d = 1; d < 16; d <<= 1) {
            Ssum[k] += __shfl_xor(Ssum[k], d);
            Tsum[k] += __shfl_xor(Tsum[k], d);
        }
    }
    float invd[5];
    #pragma unroll
    for (int k = 0; k < 5; ++k)
        invd[k] = 1.0f / (Tsum[k] + 1e-8f * Ssum[k]);

    // ---- epilogue: transpose via An4 region, XOR-swizzled rows ----
    // Invariant: LDS position q of channel ch holds row (q ^ sw(ch)),
    // sw(ch) = (ch&3)<<2. Write: pos = i ^ sw. Read: the float4 at aligned
    // position q = i4*4 holds rows (q^sw)..(q^sw)+3 -> store at n0 + (q^sw).
    __syncthreads();                   // all waves done with PV & QK^T reads
    float* As = reinterpret_cast<float*>(An4);       // [c][pos] : c*80 + pos
    #pragma unroll
    for (int k = 0; k < 5; ++k)
        #pragma unroll
        for (int cc = 0; cc < 8; ++cc) {
            const int ch = tj + 16 * cc;
            const int sw = (ch & 3) << 2;
            As[ch * 80 + ((ti + 16 * k) ^ sw)] = acc[k][cc] * invd[k];
        }
    __syncthreads();
    #pragma unroll
    for (int k = 0; k < 10; ++k) {
        int f  = tid + 256 * k;
        int c  = f / 20;
        int i4 = f % 20;
        const int sw = (c & 3) << 2;
        const int q  = i4 * 4;                        // aligned LDS block
        const float4 v = *reinterpret_cast<const float4*>(&As[c * 80 + q]);
        *reinterpret_cast<float4*>(
            out + ((size_t)b * C_ + c) * N_ + n0 + (q ^ sw)) = v;
    }
}

// ---------------- InstanceNorm (in-place on out), exact two-pass ----------------
__global__ __launch_bounds__(256, 4) void glom_inorm_kernel(
    float* __restrict__ out, const float* __restrict__ gamma,
    const float* __restrict__ beta)
{
    const int row = blockIdx.x;               // b*128 + c
    const int c   = row & (C_ - 1);
    float* p = out + (size_t)row * N_;
    const int t = threadIdx.x;

    float v[5];
    float sm = 0.0f;
    #pragma unroll
    for (int k = 0; k < 5; ++k) { v[k] = p[t + 256 * k]; sm += v[k]; }
    #pragma unroll
    for (int d = 1; d < 64; d <<= 1) sm += __shfl_xor(sm, d);

    __shared__ float red[4];
    const int wid = t >> 6;
    if ((t & 63) == 0) red[wid] = sm;
    __syncthreads();
    const float mu = (red[0] + red[1] + red[2] + red[3]) * (1.0f / (float)N_);

    float sq = 0.0f;
    #pragma unroll
    for (int k = 0; k < 5; ++k) { float d0 = v[k] - mu; sq += d0 * d0; }
    #pragma unroll
    for (int d = 1; d < 64; d <<= 1) sq += __shfl_xor(sq, d);
    __syncthreads();                           // red reads done before reuse
    if ((t & 63) == 0) red[wid] = sq;
    __syncthreads();
    const float var = (red[0] + red[1] + red[2] + red[3]) * (1.0f / (float)N_);
    const float rs  = rsqrtf(var + 1e-5f);
    const float g   = gamma[c];
    const float be  = beta[c];
    #pragma unroll
    for (int k = 0; k < 5; ++k)
        p[t + 256 * k] = (v[k] - mu) * rs * g + be;
}

extern "C" void kernel_launch(void* const* d_in, const int* in_sizes, int n_in,
                              void* d_out, int out_size, void* d_ws, size_t ws_size,
                              hipStream_t stream)
{
    (void)in_sizes; (void)n_in; (void)out_size; (void)d_ws; (void)ws_size;
    const float* x     = (const float*)d_in[0];
    const float* probs = (const float*)d_in[1];
    const float* gamma = (const float*)d_in[2];
    const float* beta  = (const float*)d_in[3];
    float* out = (float*)d_out;

    glom_attn_kernel<<<dim3(256), dim3(256), 0, stream>>>(x, probs, out);
    glom_inorm_kernel<<<dim3(B_ * C_), dim3(256), 0, stream>>>(out, gamma, beta);
}

// Round 10
// 126.381 us; speedup vs baseline: 2.2219x; 2.2219x over previous
//
#include <hip/hip_runtime.h>
#include <hip/hip_bf16.h>

// GLOM level-1: fused similarity-attention (prob-reweighted) + InstanceNorm.
// B=16, C=128, H=32, W=40 -> N=1280.
//
// MFMA (bf16) version. Math (denominator-cancelled softmax, exact vs ref):
//   e[n,m] = exp(dot(x_n,x_m)/(1.2*sqrt(128)))
//   S[n] = sum_m e, T[n] = sum_m e*p,  out_pre[n,c] = sum_m e*p*X[c][m] / (T+1e-8*S)
// attn kernel: grid 256 = (batch, 80-row tile), block 256 (4 waves).
//   Loop over 10 m-chunks of 128:
//     stage Xm[c][m] + XmT[m][c] (bf16, LDS) -> QK^T MFMA (wave w owns m-cols
//     32w..32w+31) -> exp*probs -> P (bf16) to LDS -> PV MFMA (wave w owns
//     channels 32w..32w+31; accumulates fp32 across all chunks).
//   Only the MFMA D-layout (HW-verified: col=lane&15, row=4*(lane>>4)+reg)
//   determines cross-domain indices; A/B k-mapping cancels between operands.
// inorm kernel: exact two-pass InstanceNorm in-place on out.

#define B_ 16
#define C_ 128
#define N_ 1280
#define BN 80
#define BM 128
#define NT 10
#define LDH 136          // bf16 row stride: 272B = 17*16B -> aligned b128, uniform banks

typedef __attribute__((ext_vector_type(8))) short short8;
typedef __attribute__((ext_vector_type(4))) float f32x4;
typedef __attribute__((ext_vector_type(4))) unsigned short us4_t;  // renamed: ushort4 collides with HIP builtin

#define MFMA16(a, bb, c) __builtin_amdgcn_mfma_f32_16x16x32_bf16((a), (bb), (c), 0, 0, 0)

__device__ __forceinline__ unsigned short f2bf(float f) {
    unsigned u = __builtin_bit_cast(unsigned, f);
    u = (u + 0x7FFFu + ((u >> 16) & 1u)) >> 16;   // RNE
    return (unsigned short)u;
}

__global__ __launch_bounds__(256, 1) void glom_attn_mfma(
    const float* __restrict__ x, const float* __restrict__ probs,
    float* __restrict__ out)
{
    __shared__ __attribute__((aligned(16))) unsigned short AnT[BN][LDH];  // [n][c]
    __shared__ __attribute__((aligned(16))) unsigned short XmT[BM][LDH];  // [m][c]
    __shared__ __attribute__((aligned(16))) unsigned short Xm [C_][LDH];  // [c][m]
    __shared__ __attribute__((aligned(16))) unsigned short Plds[BN][LDH]; // [n][m]
    __shared__ float Sred[4][BN], Tred[4][BN], invd_s[BN];

    const int tid = threadIdx.x;
    const int w   = tid >> 6;        // wave 0..3
    const int l   = tid & 63;
    const int a   = l & 15;          // MFMA lane col
    const int g   = l >> 4;          // MFMA lane group

    const int L  = blockIdx.x;       // XCD-locality swizzle (same as fp32 version)
    const int b  = (L & 7) + 8 * (L >> 7);
    const int nt = (L >> 3) & 15;
    const int n0 = nt * BN;
    const float* Xb = x + (size_t)b * C_ * N_;

    const float INV_SCALE = 0.07365695637359846f;  // 1/(1.2*sqrt(128))

    // ---- stage AnT once: AnT[i][c] = bf16(X[c][n0+i]) ----
    #pragma unroll
    for (int k = 0; k < 10; ++k) {
        int f  = tid + 256 * k;          // 0..2559 float4s
        int c  = f / 20;
        int i4 = f % 20;
        const float4 v = *reinterpret_cast<const float4*>(Xb + c * N_ + n0 + i4 * 4);
        AnT[i4 * 4 + 0][c] = f2bf(v.x);
        AnT[i4 * 4 + 1][c] = f2bf(v.y);
        AnT[i4 * 4 + 2][c] = f2bf(v.z);
        AnT[i4 * 4 + 3][c] = f2bf(v.w);
    }

    f32x4 Y[2][5];                   // PV acc: [cl][nt2], ch = 32w+16cl+4g+rr, n = 16nt2+a
    #pragma unroll
    for (int cl = 0; cl < 2; ++cl)
        #pragma unroll
        for (int nt2 = 0; nt2 < 5; ++nt2)
            #pragma unroll
            for (int rr = 0; rr < 4; ++rr) Y[cl][nt2][rr] = 0.0f;

    float Sp[5][4], Tp[5][4];        // row-sum partials: row n = 16nt2+4g+rr, this lane's m-cols
    #pragma unroll
    for (int nt2 = 0; nt2 < 5; ++nt2)
        #pragma unroll
        for (int rr = 0; rr < 4; ++rr) { Sp[nt2][rr] = 0.0f; Tp[nt2][rr] = 0.0f; }

    const int cg = tid >> 3, mg = tid & 7;   // staging decomposition

    for (int mt = 0; mt < NT; ++mt) {
        const int mg0 = mt * BM;
        __syncthreads();             // prev-chunk PV reads done before overwrite

        // ---- stage Xm (c-major) + XmT (m-major), bf16 ----
        #pragma unroll
        for (int q = 0; q < 4; ++q) {
            const int mcol = mg0 + 4 * mg + 32 * q;
            const float4 r0 = *reinterpret_cast<const float4*>(Xb + (4*cg+0)*N_ + mcol);
            const float4 r1 = *reinterpret_cast<const float4*>(Xb + (4*cg+1)*N_ + mcol);
            const float4 r2 = *reinterpret_cast<const float4*>(Xb + (4*cg+2)*N_ + mcol);
            const float4 r3 = *reinterpret_cast<const float4*>(Xb + (4*cg+3)*N_ + mcol);
            const int ml = 4 * mg + 32 * q;
            *reinterpret_cast<us4_t*>(&Xm[4*cg+0][ml]) = (us4_t){f2bf(r0.x), f2bf(r0.y), f2bf(r0.z), f2bf(r0.w)};
            *reinterpret_cast<us4_t*>(&Xm[4*cg+1][ml]) = (us4_t){f2bf(r1.x), f2bf(r1.y), f2bf(r1.z), f2bf(r1.w)};
            *reinterpret_cast<us4_t*>(&Xm[4*cg+2][ml]) = (us4_t){f2bf(r2.x), f2bf(r2.y), f2bf(r2.z), f2bf(r2.w)};
            *reinterpret_cast<us4_t*>(&Xm[4*cg+3][ml]) = (us4_t){f2bf(r3.x), f2bf(r3.y), f2bf(r3.z), f2bf(r3.w)};
            *reinterpret_cast<unsigned*>(&XmT[ml+0][4*cg+0]) = (unsigned)f2bf(r0.x) | ((unsigned)f2bf(r1.x) << 16);
            *reinterpret_cast<unsigned*>(&XmT[ml+0][4*cg+2]) = (unsigned)f2bf(r2.x) | ((unsigned)f2bf(r3.x) << 16);
            *reinterpret_cast<unsigned*>(&XmT[ml+1][4*cg+0]) = (unsigned)f2bf(r0.y) | ((unsigned)f2bf(r1.y) << 16);
            *reinterpret_cast<unsigned*>(&XmT[ml+1][4*cg+2]) = (unsigned)f2bf(r2.y) | ((unsigned)f2bf(r3.y) << 16);
            *reinterpret_cast<unsigned*>(&XmT[ml+2][4*cg+0]) = (unsigned)f2bf(r0.z) | ((unsigned)f2bf(r1.z) << 16);
            *reinterpret_cast<unsigned*>(&XmT[ml+2][4*cg+2]) = (unsigned)f2bf(r2.z) | ((unsigned)f2bf(r3.z) << 16);
            *reinterpret_cast<unsigned*>(&XmT[ml+3][4*cg+0]) = (unsigned)f2bf(r0.w) | ((unsigned)f2bf(r1.w) << 16);
            *reinterpret_cast<unsigned*>(&XmT[ml+3][4*cg+2]) = (unsigned)f2bf(r2.w) | ((unsigned)f2bf(r3.w) << 16);
        }
        __syncthreads();

        // ---- QK^T: wave w computes S for m-cols 32w..32w+31 (two 16-m tiles) ----
        f32x4 d1[2][5];
        #pragma unroll
        for (int jj = 0; jj < 2; ++jj)
            #pragma unroll
            for (int nt2 = 0; nt2 < 5; ++nt2)
                #pragma unroll
                for (int rr = 0; rr < 4; ++rr) d1[jj][nt2][rr] = 0.0f;

        #pragma unroll
        for (int ks = 0; ks < 4; ++ks) {
            const short8 b0 = *reinterpret_cast<const short8*>(&XmT[32*w      + a][32*ks + 8*g]);
            const short8 b1 = *reinterpret_cast<const short8*>(&XmT[32*w + 16 + a][32*ks + 8*g]);
            #pragma unroll
            for (int nt2 = 0; nt2 < 5; ++nt2) {
                const short8 a1 = *reinterpret_cast<const short8*>(&AnT[16*nt2 + a][32*ks + 8*g]);
                d1[0][nt2] = MFMA16(a1, b0, d1[0][nt2]);
                d1[1][nt2] = MFMA16(a1, b1, d1[1][nt2]);
            }
        }

        // ---- exp * probs, S/T partials, P -> LDS (bf16) ----
        #pragma unroll
        for (int jj = 0; jj < 2; ++jj) {
            #pragma unroll
            for (int nt2 = 0; nt2 < 5; ++nt2) {
                const int mcol = mg0 + 32*w + 16*jj + a;
                const size_t pbase = (size_t)(n0 + 16*nt2 + 4*g) * N_ + mcol;
                #pragma unroll
                for (int rr = 0; rr < 4; ++rr) {
                    const float e  = __expf(d1[jj][nt2][rr] * INV_SCALE);
                    const float p  = probs[pbase + (size_t)rr * N_];
                    const float wv = e * p;
                    Sp[nt2][rr] += e;
                    Tp[nt2][rr] += wv;
                    Plds[16*nt2 + 4*g + rr][32*w + 16*jj + a] = f2bf(wv);
                }
            }
        }
        __syncthreads();             // P visible to all waves

        // ---- PV: wave w owns channels 32w..32w+31, accumulates over this chunk ----
        #pragma unroll
        for (int ks2 = 0; ks2 < 4; ++ks2) {
            const short8 a20 = *reinterpret_cast<const short8*>(&Xm[32*w      + a][32*ks2 + 8*g]);
            const short8 a21 = *reinterpret_cast<const short8*>(&Xm[32*w + 16 + a][32*ks2 + 8*g]);
            #pragma unroll
            for (int nt2 = 0; nt2 < 5; ++nt2) {
                const short8 b2 = *reinterpret_cast<const short8*>(&Plds[16*nt2 + a][32*ks2 + 8*g]);
                Y[0][nt2] = MFMA16(a20, b2, Y[0][nt2]);
                Y[1][nt2] = MFMA16(a21, b2, Y[1][nt2]);
            }
        }
    }

    // ---- row sums: reduce over the 16 a-lanes, then across waves via LDS ----
    #pragma unroll
    for (int nt2 = 0; nt2 < 5; ++nt2)
        #pragma unroll
        for (int rr = 0; rr < 4; ++rr) {
            #pragma unroll
            for (int d = 1; d < 16; d <<= 1) {
                Sp[nt2][rr] += __shfl_xor(Sp[nt2][rr], d);
                Tp[nt2][rr] += __shfl_xor(Tp[nt2][rr], d);
            }
        }
    if (a == 0) {
        #pragma unroll
        for (int nt2 = 0; nt2 < 5; ++nt2)
            #pragma unroll
            for (int rr = 0; rr < 4; ++rr) {
                Sred[w][16*nt2 + 4*g + rr] = Sp[nt2][rr];
                Tred[w][16*nt2 + 4*g + rr] = Tp[nt2][rr];
            }
    }
    __syncthreads();
    if (tid < BN) {
        const float S = Sred[0][tid] + Sred[1][tid] + Sred[2][tid] + Sred[3][tid];
        const float T = Tred[0][tid] + Tred[1][tid] + Tred[2][tid] + Tred[3][tid];
        invd_s[tid] = 1.0f / (T + 1e-8f * S);
    }
    __syncthreads();

    // ---- store: out[b][ch][n] = Y * invd[n] ----
    #pragma unroll
    for (int nt2 = 0; nt2 < 5; ++nt2) {
        const float iv = invd_s[16*nt2 + a];
        #pragma unroll
        for (int cl = 0; cl < 2; ++cl)
            #pragma unroll
            for (int rr = 0; rr < 4; ++rr)
                out[((size_t)b * C_ + 32*w + 16*cl + 4*g + rr) * N_ + n0 + 16*nt2 + a]
                    = Y[cl][nt2][rr] * iv;
    }
}

// ---------------- InstanceNorm (in-place on out), exact two-pass ----------------
__global__ __launch_bounds__(256, 4) void glom_inorm_kernel(
    float* __restrict__ out, const float* __restrict__ gamma,
    const float* __restrict__ beta)
{
    const int row = blockIdx.x;               // b*128 + c
    const int c   = row & (C_ - 1);
    float* p = out + (size_t)row * N_;
    const int t = threadIdx.x;

    float v[5];
    float sm = 0.0f;
    #pragma unroll
    for (int k = 0; k < 5; ++k) { v[k] = p[t + 256 * k]; sm += v[k]; }
    #pragma unroll
    for (int d = 1; d < 64; d <<= 1) sm += __shfl_xor(sm, d);

    __shared__ float red[4];
    const int wid = t >> 6;
    if ((t & 63) == 0) red[wid] = sm;
    __syncthreads();
    const float mu = (red[0] + red[1] + red[2] + red[3]) * (1.0f / (float)N_);

    float sq = 0.0f;
    #pragma unroll
    for (int k = 0; k < 5; ++k) { float d0 = v[k] - mu; sq += d0 * d0; }
    #pragma unroll
    for (int d = 1; d < 64; d <<= 1) sq += __shfl_xor(sq, d);
    __syncthreads();
    if ((t & 63) == 0) red[wid] = sq;
    __syncthreads();
    const float var = (red[0] + red[1] + red[2] + red[3]) * (1.0f / (float)N_);
    const float rs  = rsqrtf(var + 1e-5f);
    const float g   = gamma[c];
    const float be  = beta[c];
    #pragma unroll
    for (int k = 0; k < 5; ++k)
        p[t + 256 * k] = (v[k] - mu) * rs * g + be;
}

extern "C" void kernel_launch(void* const* d_in, const int* in_sizes, int n_in,
                              void* d_out, int out_size, void* d_ws, size_t ws_size,
                              hipStream_t stream)
{
    (void)in_sizes; (void)n_in; (void)out_size; (void)d_ws; (void)ws_size;
    const float* x     = (const float*)d_in[0];
    const float* probs = (const float*)d_in[1];
    const float* gamma = (const float*)d_in[2];
    const float* beta  = (const float*)d_in[3];
    float* out = (float*)d_out;

    glom_attn_mfma<<<dim3(256), dim3(256), 0, stream>>>(x, probs, out);
    glom_inorm_kernel<<<dim3(B_ * C_), dim3(256), 0, stream>>>(out, gamma, beta);
}

// Round 11
// 120.590 us; speedup vs baseline: 2.3286x; 1.0480x over previous
//
#include <hip/hip_runtime.h>
#include <hip/hip_bf16.h>

// GLOM level-1: fused similarity-attention (prob-reweighted) + InstanceNorm.
// B=16, C=128, H=32, W=40 -> N=1280.
//
// MFMA (bf16), 8-wave version. Math (denominator-cancelled softmax, == ref):
//   e[n,m] = exp(dot(x_n,x_m)/(1.2*sqrt(128)))
//   S[n] = sum_m e, T[n] = sum_m e*p,  out_pre[n,c] = sum_m e*p*X[c][m] / (T+1e-8*S)
// attn kernel: grid 256 = (batch, 80-row tile), block 512 (8 waves, 2/SIMD).
//   Loop over 10 m-chunks of 128:
//     stage Xm[c][m] + XmT[m][c] (bf16 LDS) ; prefetch probs->regs ; barrier
//     QK^T MFMA (wave w owns m-cols 16w..16w+15) -> exp*probs -> P (bf16) LDS
//     barrier -> PV MFMA (wave w owns channels 16w..16w+15; fp32 acc).
//   R10 verified this structure at 4 waves (pass, absmax 0.031); this round
//   only re-splits wave ownership (jj/cl loops -> w) + adds probs prefetch.
// inorm kernel: exact two-pass InstanceNorm in-place on out (unchanged).

#define B_ 16
#define C_ 128
#define N_ 1280
#define BN 80
#define BM 128
#define NT 10
#define LDH 136          // bf16 row stride: 272B = 17*16B -> aligned b128, uniform banks

typedef __attribute__((ext_vector_type(8))) short short8;
typedef __attribute__((ext_vector_type(4))) float f32x4;
typedef __attribute__((ext_vector_type(4))) unsigned short us4_t;  // ushort4 collides with HIP builtin

#define MFMA16(a, bb, c) __builtin_amdgcn_mfma_f32_16x16x32_bf16((a), (bb), (c), 0, 0, 0)

__device__ __forceinline__ unsigned short f2bf(float f) {
    unsigned u = __builtin_bit_cast(unsigned, f);
    u = (u + 0x7FFFu + ((u >> 16) & 1u)) >> 16;   // RNE
    return (unsigned short)u;
}

__global__ __launch_bounds__(512, 1) void glom_attn_mfma(
    const float* __restrict__ x, const float* __restrict__ probs,
    float* __restrict__ out)
{
    __shared__ __attribute__((aligned(16))) unsigned short AnT[BN][LDH];  // [n][c]
    __shared__ __attribute__((aligned(16))) unsigned short XmT[BM][LDH];  // [m][c]
    __shared__ __attribute__((aligned(16))) unsigned short Xm [C_][LDH];  // [c][m]
    __shared__ __attribute__((aligned(16))) unsigned short Plds[BN][LDH]; // [n][m]
    __shared__ float Sred[8][BN], Tred[8][BN], invd_s[BN];

    const int tid = threadIdx.x;
    const int w   = tid >> 6;        // wave 0..7
    const int l   = tid & 63;
    const int a   = l & 15;          // MFMA lane col
    const int g   = l >> 4;          // MFMA lane group

    const int L  = blockIdx.x;       // XCD-locality swizzle
    const int b  = (L & 7) + 8 * (L >> 7);
    const int nt = (L >> 3) & 15;
    const int n0 = nt * BN;
    const float* Xb = x + (size_t)b * C_ * N_;

    const float INV_SCALE = 0.07365695637359846f;  // 1/(1.2*sqrt(128))

    // ---- stage AnT once: AnT[i][c] = bf16(X[c][n0+i]) ----
    #pragma unroll
    for (int k = 0; k < 5; ++k) {
        int f  = tid + 512 * k;          // 0..2559 float4s
        int c  = f / 20;
        int i4 = f % 20;
        const float4 v = *reinterpret_cast<const float4*>(Xb + c * N_ + n0 + i4 * 4);
        AnT[i4 * 4 + 0][c] = f2bf(v.x);
        AnT[i4 * 4 + 1][c] = f2bf(v.y);
        AnT[i4 * 4 + 2][c] = f2bf(v.z);
        AnT[i4 * 4 + 3][c] = f2bf(v.w);
    }

    f32x4 Y[5];                      // PV acc: ch = 16w+4g+rr, n = 16nt2+a
    #pragma unroll
    for (int nt2 = 0; nt2 < 5; ++nt2)
        #pragma unroll
        for (int rr = 0; rr < 4; ++rr) Y[nt2][rr] = 0.0f;

    float Sp[5][4], Tp[5][4];        // partials: row n = 16nt2+4g+rr, this lane's m-col
    #pragma unroll
    for (int nt2 = 0; nt2 < 5; ++nt2)
        #pragma unroll
        for (int rr = 0; rr < 4; ++rr) { Sp[nt2][rr] = 0.0f; Tp[nt2][rr] = 0.0f; }

    const int cg = tid >> 4, mg = tid & 15;   // staging: channels 4cg..4cg+3, cols 4mg+64q

    for (int mt = 0; mt < NT; ++mt) {
        const int mg0 = mt * BM;
        __syncthreads();             // prev-chunk PV reads done before overwrite

        // ---- stage Xm (c-major) + XmT (m-major), bf16 ----
        #pragma unroll
        for (int q = 0; q < 2; ++q) {
            const int mcol = mg0 + 4 * mg + 64 * q;
            const float4 r0 = *reinterpret_cast<const float4*>(Xb + (4*cg+0)*N_ + mcol);
            const float4 r1 = *reinterpret_cast<const float4*>(Xb + (4*cg+1)*N_ + mcol);
            const float4 r2 = *reinterpret_cast<const float4*>(Xb + (4*cg+2)*N_ + mcol);
            const float4 r3 = *reinterpret_cast<const float4*>(Xb + (4*cg+3)*N_ + mcol);
            const int ml = 4 * mg + 64 * q;
            *reinterpret_cast<us4_t*>(&Xm[4*cg+0][ml]) = (us4_t){f2bf(r0.x), f2bf(r0.y), f2bf(r0.z), f2bf(r0.w)};
            *reinterpret_cast<us4_t*>(&Xm[4*cg+1][ml]) = (us4_t){f2bf(r1.x), f2bf(r1.y), f2bf(r1.z), f2bf(r1.w)};
            *reinterpret_cast<us4_t*>(&Xm[4*cg+2][ml]) = (us4_t){f2bf(r2.x), f2bf(r2.y), f2bf(r2.z), f2bf(r2.w)};
            *reinterpret_cast<us4_t*>(&Xm[4*cg+3][ml]) = (us4_t){f2bf(r3.x), f2bf(r3.y), f2bf(r3.z), f2bf(r3.w)};
            *reinterpret_cast<unsigned*>(&XmT[ml+0][4*cg+0]) = (unsigned)f2bf(r0.x) | ((unsigned)f2bf(r1.x) << 16);
            *reinterpret_cast<unsigned*>(&XmT[ml+0][4*cg+2]) = (unsigned)f2bf(r2.x) | ((unsigned)f2bf(r3.x) << 16);
            *reinterpret_cast<unsigned*>(&XmT[ml+1][4*cg+0]) = (unsigned)f2bf(r0.y) | ((unsigned)f2bf(r1.y) << 16);
            *reinterpret_cast<unsigned*>(&XmT[ml+1][4*cg+2]) = (unsigned)f2bf(r2.y) | ((unsigned)f2bf(r3.y) << 16);
            *reinterpret_cast<unsigned*>(&XmT[ml+2][4*cg+0]) = (unsigned)f2bf(r0.z) | ((unsigned)f2bf(r1.z) << 16);
            *reinterpret_cast<unsigned*>(&XmT[ml+2][4*cg+2]) = (unsigned)f2bf(r2.z) | ((unsigned)f2bf(r3.z) << 16);
            *reinterpret_cast<unsigned*>(&XmT[ml+3][4*cg+0]) = (unsigned)f2bf(r0.w) | ((unsigned)f2bf(r1.w) << 16);
            *reinterpret_cast<unsigned*>(&XmT[ml+3][4*cg+2]) = (unsigned)f2bf(r2.w) | ((unsigned)f2bf(r3.w) << 16);
        }

        // ---- prefetch probs for this chunk (independent of LDS/barrier;
        //      latency hides under barrier drain + QK^T MFMAs) ----
        float pr[5][4];
        #pragma unroll
        for (int nt2 = 0; nt2 < 5; ++nt2) {
            const size_t pbase = (size_t)(n0 + 16*nt2 + 4*g) * N_ + mg0 + 16*w + a;
            #pragma unroll
            for (int rr = 0; rr < 4; ++rr)
                pr[nt2][rr] = probs[pbase + (size_t)rr * N_];
        }
        __syncthreads();

        // ---- QK^T: wave w computes S for m-cols 16w..16w+15 ----
        f32x4 d1[5];
        #pragma unroll
        for (int nt2 = 0; nt2 < 5; ++nt2)
            #pragma unroll
            for (int rr = 0; rr < 4; ++rr) d1[nt2][rr] = 0.0f;

        #pragma unroll
        for (int ks = 0; ks < 4; ++ks) {
            const short8 b0 = *reinterpret_cast<const short8*>(&XmT[16*w + a][32*ks + 8*g]);
            #pragma unroll
            for (int nt2 = 0; nt2 < 5; ++nt2) {
                const short8 a1 = *reinterpret_cast<const short8*>(&AnT[16*nt2 + a][32*ks + 8*g]);
                d1[nt2] = MFMA16(a1, b0, d1[nt2]);
            }
        }

        // ---- exp * probs, S/T partials, P -> LDS (bf16) ----
        #pragma unroll
        for (int nt2 = 0; nt2 < 5; ++nt2) {
            #pragma unroll
            for (int rr = 0; rr < 4; ++rr) {
                const float e  = __expf(d1[nt2][rr] * INV_SCALE);
                const float wv = e * pr[nt2][rr];
                Sp[nt2][rr] += e;
                Tp[nt2][rr] += wv;
                Plds[16*nt2 + 4*g + rr][16*w + a] = f2bf(wv);
            }
        }
        __syncthreads();             // P visible to all waves

        // ---- PV: wave w owns channels 16w..16w+15, accumulates over chunk ----
        #pragma unroll
        for (int ks2 = 0; ks2 < 4; ++ks2) {
            const short8 a2 = *reinterpret_cast<const short8*>(&Xm[16*w + a][32*ks2 + 8*g]);
            #pragma unroll
            for (int nt2 = 0; nt2 < 5; ++nt2) {
                const short8 b2 = *reinterpret_cast<const short8*>(&Plds[16*nt2 + a][32*ks2 + 8*g]);
                Y[nt2] = MFMA16(a2, b2, Y[nt2]);
            }
        }
    }

    // ---- row sums: reduce over the 16 a-lanes, then across 8 waves via LDS ----
    #pragma unroll
    for (int nt2 = 0; nt2 < 5; ++nt2)
        #pragma unroll
        for (int rr = 0; rr < 4; ++rr) {
            #pragma unroll
            for (int d = 1; d < 16; d <<= 1) {
                Sp[nt2][rr] += __shfl_xor(Sp[nt2][rr], d);
                Tp[nt2][rr] += __shfl_xor(Tp[nt2][rr], d);
            }
        }
    if (a == 0) {
        #pragma unroll
        for (int nt2 = 0; nt2 < 5; ++nt2)
            #pragma unroll
            for (int rr = 0; rr < 4; ++rr) {
                Sred[w][16*nt2 + 4*g + rr] = Sp[nt2][rr];
                Tred[w][16*nt2 + 4*g + rr] = Tp[nt2][rr];
            }
    }
    __syncthreads();
    if (tid < BN) {
        float S = 0.0f, T = 0.0f;
        #pragma unroll
        for (int ww = 0; ww < 8; ++ww) { S += Sred[ww][tid]; T += Tred[ww][tid]; }
        invd_s[tid] = 1.0f / (T + 1e-8f * S);
    }
    __syncthreads();

    // ---- store: out[b][ch][n] = Y * invd[n], ch = 16w+4g+rr ----
    #pragma unroll
    for (int nt2 = 0; nt2 < 5; ++nt2) {
        const float iv = invd_s[16*nt2 + a];
        #pragma unroll
        for (int rr = 0; rr < 4; ++rr)
            out[((size_t)b * C_ + 16*w + 4*g + rr) * N_ + n0 + 16*nt2 + a]
                = Y[nt2][rr] * iv;
    }
}

// ---------------- InstanceNorm (in-place on out), exact two-pass ----------------
__global__ __launch_bounds__(256, 4) void glom_inorm_kernel(
    float* __restrict__ out, const float* __restrict__ gamma,
    const float* __restrict__ beta)
{
    const int row = blockIdx.x;               // b*128 + c
    const int c   = row & (C_ - 1);
    float* p = out + (size_t)row * N_;
    const int t = threadIdx.x;

    float v[5];
    float sm = 0.0f;
    #pragma unroll
    for (int k = 0; k < 5; ++k) { v[k] = p[t + 256 * k]; sm += v[k]; }
    #pragma unroll
    for (int d = 1; d < 64; d <<= 1) sm += __shfl_xor(sm, d);

    __shared__ float red[4];
    const int wid = t >> 6;
    if ((t & 63) == 0) red[wid] = sm;
    __syncthreads();
    const float mu = (red[0] + red[1] + red[2] + red[3]) * (1.0f / (float)N_);

    float sq = 0.0f;
    #pragma unroll
    for (int k = 0; k < 5; ++k) { float d0 = v[k] - mu; sq += d0 * d0; }
    #pragma unroll
    for (int d = 1; d < 64; d <<= 1) sq += __shfl_xor(sq, d);
    __syncthreads();
    if ((t & 63) == 0) red[wid] = sq;
    __syncthreads();
    const float var = (red[0] + red[1] + red[2] + red[3]) * (1.0f / (float)N_);
    const float rs  = rsqrtf(var + 1e-5f);
    const float g   = gamma[c];
    const float be  = beta[c];
    #pragma unroll
    for (int k = 0; k < 5; ++k)
        p[t + 256 * k] = (v[k] - mu) * rs * g + be;
}

extern "C" void kernel_launch(void* const* d_in, const int* in_sizes, int n_in,
                              void* d_out, int out_size, void* d_ws, size_t ws_size,
                              hipStream_t stream)
{
    (void)in_sizes; (void)n_in; (void)out_size; (void)d_ws; (void)ws_size;
    const float* x     = (const float*)d_in[0];
    const float* probs = (const float*)d_in[1];
    const float* gamma = (const float*)d_in[2];
    const float* beta  = (const float*)d_in[3];
    float* out = (float*)d_out;

    glom_attn_mfma<<<dim3(256), dim3(512), 0, stream>>>(x, probs, out);
    glom_inorm_kernel<<<dim3(B_ * C_), dim3(256), 0, stream>>>(out, gamma, beta);
}

// Round 12
// 117.700 us; speedup vs baseline: 2.3858x; 1.0246x over previous
//
#include <hip/hip_runtime.h>
#include <hip/hip_bf16.h>

// GLOM level-1: fused similarity-attention (prob-reweighted) + InstanceNorm.
// B=16, C=128, H=32, W=40 -> N=1280.
//
// MFMA (bf16), 8-wave version. Math (denominator-cancelled softmax, == ref):
//   e[n,m] = exp(dot(x_n,x_m)/(1.2*sqrt(128)))
//   S[n] = sum_m e, T[n] = sum_m e*p,  out_pre[n,c] = sum_m e*p*X[c][m] / (T+1e-8*S)
// attn kernel: grid 256 = (batch, 80-row tile), block 512 (8 waves, 2/SIMD).
//   A-fragments (AnT) are chunk-invariant -> hoisted to registers ONCE
//   (afr[5][4], 80 VGPR) instead of 20 ds_read_b128 per wave per chunk.
//   XmT staging writes merged to b64 (halves the 8-lanes/bank conflict source).
//   Loop over 10 m-chunks of 128:
//     stage Xm[c][m] + XmT[m][c] (bf16 LDS) ; prefetch probs->regs ; barrier
//     QK^T MFMA (wave w owns m-cols 16w..16w+15) -> exp*probs -> P (bf16) LDS
//     barrier -> PV MFMA (wave w owns channels 16w..16w+15; fp32 acc).
// inorm kernel: one wave per (b,c) row, float4, shuffle-only (no LDS).

#define B_ 16
#define C_ 128
#define N_ 1280
#define BN 80
#define BM 128
#define NT 10
#define LDH 136          // bf16 row stride: 272B = 17*16B -> aligned b128, uniform banks

typedef __attribute__((ext_vector_type(8))) short short8;
typedef __attribute__((ext_vector_type(4))) float f32x4;
typedef __attribute__((ext_vector_type(4))) unsigned short us4_t;  // ushort4 collides with HIP builtin

#define MFMA16(a, bb, c) __builtin_amdgcn_mfma_f32_16x16x32_bf16((a), (bb), (c), 0, 0, 0)

__device__ __forceinline__ unsigned short f2bf(float f) {
    unsigned u = __builtin_bit_cast(unsigned, f);
    u = (u + 0x7FFFu + ((u >> 16) & 1u)) >> 16;   // RNE
    return (unsigned short)u;
}

__global__ __launch_bounds__(512, 1) void glom_attn_mfma(
    const float* __restrict__ x, const float* __restrict__ probs,
    float* __restrict__ out)
{
    __shared__ __attribute__((aligned(16))) unsigned short AnT[BN][LDH];  // [n][c] (read once, for hoist)
    __shared__ __attribute__((aligned(16))) unsigned short XmT[BM][LDH];  // [m][c]
    __shared__ __attribute__((aligned(16))) unsigned short Xm [C_][LDH];  // [c][m]
    __shared__ __attribute__((aligned(16))) unsigned short Plds[BN][LDH]; // [n][m]
    __shared__ float Sred[8][BN], Tred[8][BN], invd_s[BN];

    const int tid = threadIdx.x;
    const int w   = tid >> 6;        // wave 0..7
    const int l   = tid & 63;
    const int a   = l & 15;          // MFMA lane col
    const int g   = l >> 4;          // MFMA lane group

    const int L  = blockIdx.x;       // XCD-locality swizzle
    const int b  = (L & 7) + 8 * (L >> 7);
    const int nt = (L >> 3) & 15;
    const int n0 = nt * BN;
    const float* Xb = x + (size_t)b * C_ * N_;

    const float INV_SCALE = 0.07365695637359846f;  // 1/(1.2*sqrt(128))

    // ---- stage AnT once: AnT[i][c] = bf16(X[c][n0+i]) ----
    #pragma unroll
    for (int k = 0; k < 5; ++k) {
        int f  = tid + 512 * k;          // 0..2559 float4s
        int c  = f / 20;
        int i4 = f % 20;
        const float4 v = *reinterpret_cast<const float4*>(Xb + c * N_ + n0 + i4 * 4);
        AnT[i4 * 4 + 0][c] = f2bf(v.x);
        AnT[i4 * 4 + 1][c] = f2bf(v.y);
        AnT[i4 * 4 + 2][c] = f2bf(v.z);
        AnT[i4 * 4 + 3][c] = f2bf(v.w);
    }
    __syncthreads();                 // AnT complete before hoist reads

    // ---- hoist A-fragments to registers (chunk-invariant) ----
    short8 afr[5][4];
    #pragma unroll
    for (int nt2 = 0; nt2 < 5; ++nt2)
        #pragma unroll
        for (int ks = 0; ks < 4; ++ks)
            afr[nt2][ks] = *reinterpret_cast<const short8*>(&AnT[16*nt2 + a][32*ks + 8*g]);

    f32x4 Y[5];                      // PV acc: ch = 16w+4g+rr, n = 16nt2+a
    #pragma unroll
    for (int nt2 = 0; nt2 < 5; ++nt2)
        #pragma unroll
        for (int rr = 0; rr < 4; ++rr) Y[nt2][rr] = 0.0f;

    float Sp[5][4], Tp[5][4];        // partials: row n = 16nt2+4g+rr, this lane's m-col
    #pragma unroll
    for (int nt2 = 0; nt2 < 5; ++nt2)
        #pragma unroll
        for (int rr = 0; rr < 4; ++rr) { Sp[nt2][rr] = 0.0f; Tp[nt2][rr] = 0.0f; }

    const int cg = tid >> 4, mg = tid & 15;   // staging: channels 4cg..4cg+3, cols 4mg+64q

    for (int mt = 0; mt < NT; ++mt) {
        const int mg0 = mt * BM;
        __syncthreads();             // prev-chunk PV reads done before overwrite

        // ---- stage Xm (c-major) + XmT (m-major), bf16; XmT as b64 writes ----
        #pragma unroll
        for (int q = 0; q < 2; ++q) {
            const int mcol = mg0 + 4 * mg + 64 * q;
            const float4 r0 = *reinterpret_cast<const float4*>(Xb + (4*cg+0)*N_ + mcol);
            const float4 r1 = *reinterpret_cast<const float4*>(Xb + (4*cg+1)*N_ + mcol);
            const float4 r2 = *reinterpret_cast<const float4*>(Xb + (4*cg+2)*N_ + mcol);
            const float4 r3 = *reinterpret_cast<const float4*>(Xb + (4*cg+3)*N_ + mcol);
            const int ml = 4 * mg + 64 * q;
            *reinterpret_cast<us4_t*>(&Xm[4*cg+0][ml]) = (us4_t){f2bf(r0.x), f2bf(r0.y), f2bf(r0.z), f2bf(r0.w)};
            *reinterpret_cast<us4_t*>(&Xm[4*cg+1][ml]) = (us4_t){f2bf(r1.x), f2bf(r1.y), f2bf(r1.z), f2bf(r1.w)};
            *reinterpret_cast<us4_t*>(&Xm[4*cg+2][ml]) = (us4_t){f2bf(r2.x), f2bf(r2.y), f2bf(r2.z), f2bf(r2.w)};
            *reinterpret_cast<us4_t*>(&Xm[4*cg+3][ml]) = (us4_t){f2bf(r3.x), f2bf(r3.y), f2bf(r3.z), f2bf(r3.w)};
            // transpose: one b64 write per m (4 channels packed)
            *reinterpret_cast<us4_t*>(&XmT[ml+0][4*cg]) = (us4_t){f2bf(r0.x), f2bf(r1.x), f2bf(r2.x), f2bf(r3.x)};
            *reinterpret_cast<us4_t*>(&XmT[ml+1][4*cg]) = (us4_t){f2bf(r0.y), f2bf(r1.y), f2bf(r2.y), f2bf(r3.y)};
            *reinterpret_cast<us4_t*>(&XmT[ml+2][4*cg]) = (us4_t){f2bf(r0.z), f2bf(r1.z), f2bf(r2.z), f2bf(r3.z)};
            *reinterpret_cast<us4_t*>(&XmT[ml+3][4*cg]) = (us4_t){f2bf(r0.w), f2bf(r1.w), f2bf(r2.w), f2bf(r3.w)};
        }

        // ---- prefetch probs for this chunk (hides under barrier + QK^T) ----
        float pr[5][4];
        #pragma unroll
        for (int nt2 = 0; nt2 < 5; ++nt2) {
            const size_t pbase = (size_t)(n0 + 16*nt2 + 4*g) * N_ + mg0 + 16*w + a;
            #pragma unroll
            for (int rr = 0; rr < 4; ++rr)
                pr[nt2][rr] = probs[pbase + (size_t)rr * N_];
        }
        __syncthreads();

        // ---- QK^T: wave w computes S for m-cols 16w..16w+15 (A from registers) ----
        f32x4 d1[5];
        #pragma unroll
        for (int nt2 = 0; nt2 < 5; ++nt2)
            #pragma unroll
            for (int rr = 0; rr < 4; ++rr) d1[nt2][rr] = 0.0f;

        #pragma unroll
        for (int ks = 0; ks < 4; ++ks) {
            const short8 b0 = *reinterpret_cast<const short8*>(&XmT[16*w + a][32*ks + 8*g]);
            #pragma unroll
            for (int nt2 = 0; nt2 < 5; ++nt2)
                d1[nt2] = MFMA16(afr[nt2][ks], b0, d1[nt2]);
        }

        // ---- exp * probs, S/T partials, P -> LDS (bf16) ----
        #pragma unroll
        for (int nt2 = 0; nt2 < 5; ++nt2) {
            #pragma unroll
            for (int rr = 0; rr < 4; ++rr) {
                const float e  = __expf(d1[nt2][rr] * INV_SCALE);
                const float wv = e * pr[nt2][rr];
                Sp[nt2][rr] += e;
                Tp[nt2][rr] += wv;
                Plds[16*nt2 + 4*g + rr][16*w + a] = f2bf(wv);
            }
        }
        __syncthreads();             // P visible to all waves

        // ---- PV: wave w owns channels 16w..16w+15, accumulates over chunk ----
        #pragma unroll
        for (int ks2 = 0; ks2 < 4; ++ks2) {
            const short8 a2 = *reinterpret_cast<const short8*>(&Xm[16*w + a][32*ks2 + 8*g]);
            #pragma unroll
            for (int nt2 = 0; nt2 < 5; ++nt2) {
                const short8 b2 = *reinterpret_cast<const short8*>(&Plds[16*nt2 + a][32*ks2 + 8*g]);
                Y[nt2] = MFMA16(a2, b2, Y[nt2]);
            }
        }
    }

    // ---- row sums: reduce over the 16 a-lanes, then across 8 waves via LDS ----
    #pragma unroll
    for (int nt2 = 0; nt2 < 5; ++nt2)
        #pragma unroll
        for (int rr = 0; rr < 4; ++rr) {
            #pragma unroll
            for (int d = 1; d < 16; d <<= 1) {
                Sp[nt2][rr] += __shfl_xor(Sp[nt2][rr], d);
                Tp[nt2][rr] += __shfl_xor(Tp[nt2][rr], d);
            }
        }
    if (a == 0) {
        #pragma unroll
        for (int nt2 = 0; nt2 < 5; ++nt2)
            #pragma unroll
            for (int rr = 0; rr < 4; ++rr) {
                Sred[w][16*nt2 + 4*g + rr] = Sp[nt2][rr];
                Tred[w][16*nt2 + 4*g + rr] = Tp[nt2][rr];
            }
    }
    __syncthreads();
    if (tid < BN) {
        float S = 0.0f, T = 0.0f;
        #pragma unroll
        for (int ww = 0; ww < 8; ++ww) { S += Sred[ww][tid]; T += Tred[ww][tid]; }
        invd_s[tid] = 1.0f / (T + 1e-8f * S);
    }
    __syncthreads();

    // ---- store: out[b][ch][n] = Y * invd[n], ch = 16w+4g+rr ----
    #pragma unroll
    for (int nt2 = 0; nt2 < 5; ++nt2) {
        const float iv = invd_s[16*nt2 + a];
        #pragma unroll
        for (int rr = 0; rr < 4; ++rr)
            out[((size_t)b * C_ + 16*w + 4*g + rr) * N_ + n0 + 16*nt2 + a]
                = Y[nt2][rr] * iv;
    }
}

// ---- InstanceNorm (in-place): one wave per (b,c) row, float4, no LDS ----
__global__ __launch_bounds__(512, 2) void glom_inorm_kernel(
    float* __restrict__ out, const float* __restrict__ gamma,
    const float* __restrict__ beta)
{
    const int w   = threadIdx.x >> 6;
    const int l   = threadIdx.x & 63;
    const int row = blockIdx.x * 8 + w;       // 0..2047 = b*128 + c
    const int c   = row & (C_ - 1);
    float* p = out + (size_t)row * N_;

    float4 v[5];
    float sm = 0.0f;
    #pragma unroll
    for (int k = 0; k < 5; ++k) {
        v[k] = *reinterpret_cast<const float4*>(p + 4 * (l + 64 * k));
        sm += (v[k].x + v[k].y) + (v[k].z + v[k].w);
    }
    #pragma unroll
    for (int d = 1; d < 64; d <<= 1) sm += __shfl_xor(sm, d);
    const float mu = sm * (1.0f / (float)N_);

    float sq = 0.0f;
    #pragma unroll
    for (int k = 0; k < 5; ++k) {
        const float dx = v[k].x - mu, dy = v[k].y - mu;
        const float dz = v[k].z - mu, dw = v[k].w - mu;
        sq += (dx * dx + dy * dy) + (dz * dz + dw * dw);
    }
    #pragma unroll
    for (int d = 1; d < 64; d <<= 1) sq += __shfl_xor(sq, d);
    const float var = sq * (1.0f / (float)N_);
    const float rs  = rsqrtf(var + 1e-5f);
    const float gm  = gamma[c];
    const float be  = beta[c];
    #pragma unroll
    for (int k = 0; k < 5; ++k) {
        float4 o;
        o.x = (v[k].x - mu) * rs * gm + be;
        o.y = (v[k].y - mu) * rs * gm + be;
        o.z = (v[k].z - mu) * rs * gm + be;
        o.w = (v[k].w - mu) * rs * gm + be;
        *reinterpret_cast<float4*>(p + 4 * (l + 64 * k)) = o;
    }
}

extern "C" void kernel_launch(void* const* d_in, const int* in_sizes, int n_in,
                              void* d_out, int out_size, void* d_ws, size_t ws_size,
                              hipStream_t stream)
{
    (void)in_sizes; (void)n_in; (void)out_size; (void)d_ws; (void)ws_size;
    const float* x     = (const float*)d_in[0];
    const float* probs = (const float*)d_in[1];
    const float* gamma = (const float*)d_in[2];
    const float* beta  = (const float*)d_in[3];
    float* out = (float*)d_out;

    glom_attn_mfma<<<dim3(256), dim3(512), 0, stream>>>(x, probs, out);
    glom_inorm_kernel<<<dim3(B_ * C_ / 8), dim3(512), 0, stream>>>(out, gamma, beta);
}